// Round 17
// baseline (122.320 us; speedup 1.0000x reference)
//
#include <hip/hip_runtime.h>
#include <hip/hip_bf16.h>

#define NND   325
#define SEQ   12
#define NT    3900            // 325*12
#define KP    352             // padded j (11 chunks of 32)
#define NC    11              // k-chunks of 32
#define CH2_SHORTS 22528      // Lcat chunk: 704 rows * 32 j (rows 0-351 L, 352-687 L^2)
#define CH2_BYTES  45056
#define COLS  48              // cols per block: 4 g-slices x 12 t
#define NROW  328             // n-minor padded row (shorts)
#define GROW  3936            // shorts per g-slice (12*328)

typedef __attribute__((ext_vector_type(8))) short short8;
typedef __attribute__((ext_vector_type(4))) float floatx4;

static __device__ __forceinline__ unsigned short f2bf(float f) {
    unsigned int u = __float_as_uint(f);
    unsigned int r = (u + 0x7fffu + ((u >> 16) & 1u)) >> 16;  // RNE
    return (unsigned short)r;
}

// image index (shorts): row m (stride KP), col j; 16B slot XOR by m bits
static __device__ __forceinline__ int xi(int m, int j) {
    int slot = (j >> 3) ^ ((m >> 1) & 3);
    return m * KP + slot * 8 + (j & 7);
}

// ---- setup: d^{-1/2} ----
__global__ void calc_dis(const float* __restrict__ adj, float* __restrict__ dis) {
    int i = blockIdx.x;
    const float* row = adj + (size_t)i * NND;
    float s = 0.f;
    for (int j = threadIdx.x; j < NND; j += 64) s += row[j];
    for (int o = 32; o; o >>= 1) s += __shfl_down(s, o);
    if (threadIdx.x == 0) dis[i] = (s > 0.f) ? rsqrtf(s) : 0.f;
}

// ---- setup (merged): blocks [0,484) build L into Lcat rows [0,352) chunk-major;
// blocks [484,532) build folded weights wflat[d][192] bf16.
__global__ void build_all(const float* __restrict__ adj, const float* __restrict__ dis,
                          unsigned short* __restrict__ Lcat,
                          const float* __restrict__ W, unsigned short* __restrict__ wflat) {
    int blk = blockIdx.x;
    if (blk < 484) {
        int s = blk * 256 + threadIdx.x;          // < 484*256 = 123904 = 11*352*32
        int c = s / 11264, r = s - c * 11264;     // r = n*32 + jj, n < 352
        int n = r >> 5, jj = r & 31;
        int j = c * 32 + jj;
        float v = 0.f;
        if (n < NND && j < NND) {
            float a = adj[(size_t)n * NND + j];
            v = ((n == j) ? 1.f : 0.f) - dis[n] * a * dis[j];
        }
        Lcat[(size_t)c * CH2_SHORTS + r] = f2bf(v);
    } else {
        int idx = (blk - 484) * 256 + threadIdx.x;
        if (idx >= 64 * 192) return;
        int d = idx / 192, k = idx - d * 192;
        int kind = k >> 6, c = k & 63;
        float wv = W[kind * 4096 + c * 64 + d];
        float w;
        if (kind == 0)      w = wv - W[2 * 4096 + c * 64 + d];
        else if (kind == 1) w = wv;
        else                w = 2.f * wv;
        wflat[idx] = f2bf(w);
    }
}

// ---- setup: L^2 via MFMA. C[n][m] = sum_k L[n,k]*L[m,k] (L symmetric -> L^2).
// One wave per (nt, mt) 16x16 tile; nt<21 (336 rows), mt<22 (352 cols).
// Reads Lcat rows [0,352), writes rows [352, 688) chunk-major.
__global__ __launch_bounds__(256) void lsq_mfma(unsigned short* Lcat) {
    int ww = blockIdx.x * 4 + (threadIdx.x >> 6);
    int nt = ww / 22, mt = ww - nt * 22;
    if (nt >= 21) return;                      // wave-uniform exit, no barriers
    const int l = threadIdx.x & 63, lm = l & 15, lg = l >> 4;
    const char* abase = (const char*)Lcat + (nt * 16 + lm) * 64 + lg * 16;
    const char* bbase = (const char*)Lcat + (mt * 16 + lm) * 64 + lg * 16;
    floatx4 acc = (floatx4){0.f, 0.f, 0.f, 0.f};
    for (int c = 0; c < NC; ++c) {
        short8 a = *(const short8*)(abase + c * CH2_BYTES);
        short8 b = *(const short8*)(bbase + c * CH2_BYTES);
        acc = __builtin_amdgcn_mfma_f32_16x16x32_bf16(a, b, acc, 0, 0, 0);
    }
    // lane holds C[nrow = nt*16+lg*4+r][mcol = mt*16+lm]
    int m = mt * 16 + lm;
    int cm = m >> 5, mw = m & 31;
    unsigned short* dst = Lcat + (size_t)cm * CH2_SHORTS
                        + (size_t)(352 + nt * 16 + lg * 4) * 32 + mw;
    #pragma unroll
    for (int r = 0; r < 4; ++r) dst[r * 32] = f2bf(acc[r]);
}

// ---- Single-pass Chebyshev: Y = L*X and Z = L^2*X in ONE k-loop.
// Block = 48 cols (4 g-slices), 448 thr (7 waves), 33.8 KB LDS.
// Wave w owns 6 tiles of the 42 = 21 Y-tiles + 21 Z-tiles. A-frags streamed
// from the concatenated Lcat (L2-hot 1KB bursts), B = X image b128 reads.
// Y then Z leave via the validated coalesced LDS-bounce copy_out.
__global__ __launch_bounds__(448, 4) void cheb_single(
        const float* __restrict__ x,
        const unsigned short* __restrict__ Lcat,
        unsigned short* __restrict__ Yg,
        unsigned short* __restrict__ Zg) {
    __shared__ __align__(16) unsigned short img[COLS * KP];   // 33792 B

    const int tid = threadIdx.x;
    int bid = blockIdx.x;
    bid = (bid & 7) * 128 + (bid >> 3);       // XCD swizzle (1024 = 8*128)
    const int g0 = bid * 4;

    const int w  = tid >> 6;                  // 0..6
    const int l  = tid & 63;
    const int lm = l & 15, lg = l >> 4;

    // per-wave A-frag bases: tiles g = w*6+i; g<21 -> L rows, else L^2 rows
    const char* lbase[6];
    #pragma unroll
    for (int i = 0; i < 6; ++i) {
        int g = w * 6 + i;
        int nrow = (g < 21) ? (g * 16 + lm) : (352 + (g - 21) * 16 + lm);
        lbase[i] = (const char*)Lcat + nrow * 64 + lg * 16;
    }

    // ---- stage X: register 4x4 transpose, 4 g x 88 jq x 3 tq = 1056 units ----
    for (int i = tid; i < 1056; i += 448) {
        int g = i / 264, r = i - g * 264;
        int jq = r / 3, tq = r - (r / 3) * 3;
        int j0 = jq * 4, t0 = tq * 4;
        float a[4][4];
        #pragma unroll
        for (int rr = 0; rr < 4; ++rr) {
            int j = j0 + rr;
            if (j < NND) {
                float4 v = *(const float4*)(x + (size_t)(g0 + g) * NT + j * SEQ + t0);
                a[rr][0] = v.x; a[rr][1] = v.y; a[rr][2] = v.z; a[rr][3] = v.w;
            } else {
                a[rr][0] = a[rr][1] = a[rr][2] = a[rr][3] = 0.f;
            }
        }
        #pragma unroll
        for (int s = 0; s < 4; ++s) {
            ushort4 o;
            o.x = f2bf(a[0][s]); o.y = f2bf(a[1][s]);
            o.z = f2bf(a[2][s]); o.w = f2bf(a[3][s]);
            *(ushort4*)&img[xi(g * SEQ + t0 + s, j0)] = o;
        }
    }
    __syncthreads();

    floatx4 acc[6][3];                // [tile-local][m-tile]
    #pragma unroll
    for (int a = 0; a < 6; ++a)
        #pragma unroll
        for (int b2 = 0; b2 < 3; ++b2) acc[a][b2] = (floatx4){0.f, 0.f, 0.f, 0.f};

    // ONE pass: C[n][m] = sum_j A[n,j] * img[m,j], A = [L ; L^2]
    for (int c = 0; c < NC; ++c) {
        short8 lf[6];
        #pragma unroll
        for (int i = 0; i < 6; ++i)
            lf[i] = *(const short8*)(lbase[i] + c * CH2_BYTES);
        #pragma unroll
        for (int ct = 0; ct < 3; ++ct) {
            short8 df = *(const short8*)&img[xi(ct * 16 + lm, c * 32 + lg * 8)];
            #pragma unroll
            for (int i = 0; i < 6; ++i)
                acc[i][ct] = __builtin_amdgcn_mfma_f32_16x16x32_bf16(
                    lf[i], df, acc[i][ct], 0, 0, 0);
        }
    }
    __syncthreads();              // all img (X) reads complete

    // ---- Y phase: store tiles g<21 into img, bounce to global ----
    #pragma unroll
    for (int i = 0; i < 6; ++i) {
        int g = w * 6 + i;
        if (g < 21) {
            int n0 = g * 16 + lg * 4;
            #pragma unroll
            for (int ct = 0; ct < 3; ++ct) {
                ushort4 u;
                u.x = f2bf(acc[i][ct][0]); u.y = f2bf(acc[i][ct][1]);
                u.z = f2bf(acc[i][ct][2]); u.w = f2bf(acc[i][ct][3]);
                *(ushort4*)&img[xi(ct * 16 + lm, n0)] = u;
            }
        }
    }
    __syncthreads();              // Y image complete
    {
        for (int i = tid; i < 4 * SEQ * 41; i += 448) {   // 1968
            int gl = i / 492, r2 = i - gl * 492;
            int t = r2 / 41, oct = r2 - t * 41;
            int m = gl * SEQ + t;
            short8 v = *(const short8*)&img[xi(m, oct * 8)];
            *(short8*)&Yg[(size_t)(g0 + gl) * GROW + t * NROW + oct * 8] = v;
        }
    }
    __syncthreads();              // Y image reads complete

    // ---- Z phase: store tiles g>=21 into img, bounce to global ----
    #pragma unroll
    for (int i = 0; i < 6; ++i) {
        int g = w * 6 + i;
        if (g >= 21) {
            int n0 = (g - 21) * 16 + lg * 4;
            #pragma unroll
            for (int ct = 0; ct < 3; ++ct) {
                ushort4 u;
                u.x = f2bf(acc[i][ct][0]); u.y = f2bf(acc[i][ct][1]);
                u.z = f2bf(acc[i][ct][2]); u.w = f2bf(acc[i][ct][3]);
                *(ushort4*)&img[xi(ct * 16 + lm, n0)] = u;
            }
        }
    }
    __syncthreads();              // Z image complete
    {
        for (int i = tid; i < 4 * SEQ * 41; i += 448) {
            int gl = i / 492, r2 = i - gl * 492;
            int t = r2 / 41, oct = r2 - t * 41;
            int m = gl * SEQ + t;
            short8 v = *(const short8*)&img[xi(m, oct * 8)];
            *(short8*)&Zg[(size_t)(g0 + gl) * GROW + t * NROW + oct * 8] = v;
        }
    }
}

// ---- Phase B (r8-validated, unchanged): out = W(64x192) x [X;Y;Z] + bias ----
__global__ __launch_bounds__(256) void mix2(
        const float* __restrict__ x,
        const unsigned short* __restrict__ Yg,
        const unsigned short* __restrict__ Zg,
        const unsigned short* __restrict__ wflat,
        const float* __restrict__ bias,
        float* __restrict__ out) {
    __shared__ __align__(16) unsigned char Bl[96 * 400];   // 38400 B
    const int tid = threadIdx.x;
    int lin = blockIdx.x;
    lin = (lin & 7) * 328 + (lin >> 3);          // XCD swizzle (2624 = 8*328)
    const int b = lin / 41;
    const int tile = lin - b * 41;
    const int nt0 = tile * 96;
    const int nn0 = tile * 8;

    for (int i = tid; i < 576; i += 256) {
        int kk = i / 192;                        // 0=X, 1=Y, 2=Z
        int r2 = i - kk * 192;
        int cq = r2 / 12;
        int tc = r2 - cq * 12;
        int k0 = kk * 64 + cq * 4;
        unsigned short hv[4][8];
        if (kk == 0) {
            int nt = nt0 + tc * 8;
            #pragma unroll
            for (int r = 0; r < 4; ++r) {
                const float* sp = x + ((size_t)b * 64 + cq * 4 + r) * NT + nt;
                float4 v0 = (nt <= NT - 4) ? *(const float4*)sp : make_float4(0.f,0.f,0.f,0.f);
                float4 v1 = (nt <= NT - 8) ? *(const float4*)(sp + 4) : make_float4(0.f,0.f,0.f,0.f);
                hv[r][0] = f2bf(v0.x); hv[r][1] = f2bf(v0.y);
                hv[r][2] = f2bf(v0.z); hv[r][3] = f2bf(v0.w);
                hv[r][4] = f2bf(v1.x); hv[r][5] = f2bf(v1.y);
                hv[r][6] = f2bf(v1.z); hv[r][7] = f2bf(v1.w);
            }
        } else {
            const unsigned short* base = (kk == 1) ? Yg : Zg;
            #pragma unroll
            for (int r = 0; r < 4; ++r) {
                short8 s = *(const short8*)(base + ((size_t)b * 64 + cq * 4 + r) * GROW
                                            + tc * NROW + nn0);
                hv[r][0] = (unsigned short)s[0]; hv[r][1] = (unsigned short)s[1];
                hv[r][2] = (unsigned short)s[2]; hv[r][3] = (unsigned short)s[3];
                hv[r][4] = (unsigned short)s[4]; hv[r][5] = (unsigned short)s[5];
                hv[r][6] = (unsigned short)s[6]; hv[r][7] = (unsigned short)s[7];
            }
        }
        const int slot = k0 >> 3;
        const int half = (k0 & 4) << 1;          // byte offset within 16B slot
        #pragma unroll
        for (int jj = 0; jj < 8; ++jj) {
            int q = (kk == 0) ? (tc * 8 + jj) : (jj * 12 + tc);
            int sl = (slot & ~3) | ((slot & 3) ^ ((q >> 3) & 3));
            ushort4 o;
            o.x = hv[0][jj]; o.y = hv[1][jj]; o.z = hv[2][jj]; o.w = hv[3][jj];
            *(ushort4*)(Bl + q * 400 + sl * 16 + half) = o;
        }
    }
    __syncthreads();

    const int w = tid >> 6;
    const int l = tid & 63;
    const int lm = l & 15, lg = l >> 4;

    floatx4 acc[6];
    #pragma unroll
    for (int i = 0; i < 6; ++i) acc[i] = (floatx4){0.f, 0.f, 0.f, 0.f};

    const int arow = w * 16 + lm;
    const unsigned short* Ab = wflat + arow * 192;
    #pragma unroll
    for (int ks = 0; ks < 6; ++ks) {
        short8 a = *(const short8*)(Ab + ks * 32 + lg * 8);
        #pragma unroll
        for (int ni = 0; ni < 6; ++ni) {
            int q = ni * 16 + lm;
            short8 bb = *(const short8*)(Bl + q * 400 + (4 * ks + (lg ^ ((q >> 3) & 3))) * 16);
            acc[ni] = __builtin_amdgcn_mfma_f32_16x16x32_bf16(a, bb, acc[ni], 0, 0, 0);
        }
    }

    float br[4];
    #pragma unroll
    for (int j = 0; j < 4; ++j) br[j] = bias[w * 16 + lg * 4 + j];
    #pragma unroll
    for (int ni = 0; ni < 6; ++ni) {
        int nt = nt0 + ni * 16 + lm;
        if (nt < NT) {
            float* op = out + ((size_t)b * 64 + w * 16 + lg * 4) * NT + nt;
            #pragma unroll
            for (int j = 0; j < 4; ++j) op[(size_t)j * NT] = acc[ni][j] + br[j];
        }
    }
}

extern "C" void kernel_launch(void* const* d_in, const int* in_sizes, int n_in,
                              void* d_out, int out_size, void* d_ws, size_t ws_size,
                              hipStream_t stream) {
    const float* x   = (const float*)d_in[0];
    const float* adj = (const float*)d_in[1];
    const float* W   = (const float*)d_in[2];
    const float* b   = (const float*)d_in[3];
    float* out = (float*)d_out;

    char* ws = (char*)d_ws;
    // layout (bytes):
    //   0        : dis    (1312)
    //   1312     : Lcat   (11*22528 bf16 = 495616) -> 496928, pad to 497024
    //   497024   : wflat  (24576) -> 521600
    //   521600   : Y'     (4096*3936 bf16 = 32243712) -> 32765312
    //   32765312 : Z'     (32243712) -> 65009024 (~62.0 MiB)
    float* dis           = (float*)(ws + 0);
    unsigned short* Lcat = (unsigned short*)(ws + 1312);
    unsigned short* wflat= (unsigned short*)(ws + 497024);
    unsigned short* Yg   = (unsigned short*)(ws + 521600);
    unsigned short* Zg   = (unsigned short*)(ws + 32765312);

    calc_dis<<<NND, 64, 0, stream>>>(adj, dis);
    build_all<<<532, 256, 0, stream>>>(adj, dis, Lcat, W, wflat);
    lsq_mfma<<<116, 256, 0, stream>>>(Lcat);
    cheb_single<<<1024, 448, 0, stream>>>(x, Lcat, Yg, Zg);
    mix2<<<2624, 256, 0, stream>>>(x, Yg, Zg, wflat, b, out);
}

// Round 18
// 103.019 us; speedup vs baseline: 1.1874x; 1.1874x over previous
//
#include <hip/hip_runtime.h>
#include <hip/hip_bf16.h>

#define NND   325
#define SEQ   12
#define NT    3900            // 325*12
#define KP    352             // padded j (11 chunks of 32)
#define NC    11              // k-chunks of 32
#define CHUNK_SHORTS 12288    // L chunk: 384 n-rows * 32 j (plain, chunk-major)
#define CHUNK_BYTES  24576
#define COLS  48              // cols per block: 4 g-slices x 12 t
#define NROW  328             // n-minor padded row (shorts)
#define GROW  3936            // shorts per g-slice (12*328)

typedef __attribute__((ext_vector_type(8))) short short8;
typedef __attribute__((ext_vector_type(4))) float floatx4;

static __device__ __forceinline__ unsigned short f2bf(float f) {
    unsigned int u = __float_as_uint(f);
    unsigned int r = (u + 0x7fffu + ((u >> 16) & 1u)) >> 16;  // RNE
    return (unsigned short)r;
}

// image index (shorts): row m (stride KP), col j; 16B slot XOR by m bits
static __device__ __forceinline__ int xi(int m, int j) {
    int slot = (j >> 3) ^ ((m >> 1) & 3);
    return m * KP + slot * 8 + (j & 7);
}

// ---- setup: d^{-1/2} ----
__global__ void calc_dis(const float* __restrict__ adj, float* __restrict__ dis) {
    int i = blockIdx.x;
    const float* row = adj + (size_t)i * NND;
    float s = 0.f;
    for (int j = threadIdx.x; j < NND; j += 64) s += row[j];
    for (int o = 32; o; o >>= 1) s += __shfl_down(s, o);
    if (threadIdx.x == 0) dis[i] = (s > 0.f) ? rsqrtf(s) : 0.f;
}

// ---- setup (merged): blocks [0,528) build L chunk-major bf16 [c][n<384][32 j];
// blocks [528,576) build folded weights wflat[d][192] bf16.
__global__ void build_all(const float* __restrict__ adj, const float* __restrict__ dis,
                          unsigned short* __restrict__ Lg2,
                          const float* __restrict__ W, unsigned short* __restrict__ wflat) {
    int blk = blockIdx.x;
    if (blk < 528) {
        int s = blk * 256 + threadIdx.x;          // < 528*256 = 135168 = NC*CHUNK_SHORTS
        int c = s / CHUNK_SHORTS, r = s - c * CHUNK_SHORTS;
        int n = r >> 5, w = r & 31;
        int j = c * 32 + w;
        float v = 0.f;
        if (n < NND && j < NND) {
            float a = adj[(size_t)n * NND + j];
            v = ((n == j) ? 1.f : 0.f) - dis[n] * a * dis[j];
        }
        Lg2[s] = f2bf(v);
    } else {
        int idx = (blk - 528) * 256 + threadIdx.x;
        if (idx >= 64 * 192) return;
        int d = idx / 192, k = idx - d * 192;
        int kind = k >> 6, c = k & 63;
        float wv = W[kind * 4096 + c * 64 + d];
        float w;
        if (kind == 0)      w = wv - W[2 * 4096 + c * 64 + d];
        else if (kind == 1) w = wv;
        else                w = 2.f * wv;
        wflat[idx] = f2bf(w);
    }
}

// ---- Fused Chebyshev double L-apply (r13-exact structure). Block = 48 cols
// (4 g-slices), 448 thr (7 waves), 33.8 KB LDS -> 4 blocks/CU. Wave w owns
// n-tiles {3w..3w+2} (21 exact). GEMM k-loop barrier-free: A = L row-frags
// streamed from global (L2-hot 1KB bursts), B = image b128 reads. Both Y and
// Z leave via the coalesced LDS-bounce copy_out.
__global__ __launch_bounds__(448, 4) void cheb_fused(
        const float* __restrict__ x,
        const unsigned short* __restrict__ Lg2,
        unsigned short* __restrict__ Yg,
        unsigned short* __restrict__ Zg) {
    __shared__ __align__(16) unsigned short img[COLS * KP];   // 33792 B

    const int tid = threadIdx.x;
    int bid = blockIdx.x;
    bid = (bid & 7) * 128 + (bid >> 3);       // XCD swizzle (1024 = 8*128)
    const int g0 = bid * 4;

    const int w  = tid >> 6;                  // 0..6
    const int l  = tid & 63;
    const int lm = l & 15, lg = l >> 4;

    // per-wave L A-frag bases, n-tiles 3w..3w+2
    const char* lbase[3];
    #pragma unroll
    for (int i = 0; i < 3; ++i) {
        int nrow = (w * 3 + i) * 16 + lm;
        lbase[i] = (const char*)Lg2 + nrow * 64 + lg * 16;
    }

    // ---- stage X: register 4x4 transpose, 4 g x 88 jq x 3 tq = 1056 units ----
    for (int i = tid; i < 1056; i += 448) {
        int g = i / 264, r = i - g * 264;
        int jq = r / 3, tq = r - (r / 3) * 3;
        int j0 = jq * 4, t0 = tq * 4;
        float a[4][4];
        #pragma unroll
        for (int rr = 0; rr < 4; ++rr) {
            int j = j0 + rr;
            if (j < NND) {
                float4 v = *(const float4*)(x + (size_t)(g0 + g) * NT + j * SEQ + t0);
                a[rr][0] = v.x; a[rr][1] = v.y; a[rr][2] = v.z; a[rr][3] = v.w;
            } else {
                a[rr][0] = a[rr][1] = a[rr][2] = a[rr][3] = 0.f;
            }
        }
        #pragma unroll
        for (int s = 0; s < 4; ++s) {
            ushort4 o;
            o.x = f2bf(a[0][s]); o.y = f2bf(a[1][s]);
            o.z = f2bf(a[2][s]); o.w = f2bf(a[3][s]);
            *(ushort4*)&img[xi(g * SEQ + t0 + s, j0)] = o;
        }
    }
    __syncthreads();

    floatx4 acc[3][3];                // [n-local][m-tile]
    auto zero_acc = [&]() {
        #pragma unroll
        for (int a = 0; a < 3; ++a)
            #pragma unroll
            for (int b2 = 0; b2 < 3; ++b2) acc[a][b2] = (floatx4){0.f, 0.f, 0.f, 0.f};
    };

    // C[n][m] = sum_j L[n,j] * img[m,j]; barrier-free k-loop (r13 form)
    auto gemm = [&]() {
        for (int c = 0; c < NC; ++c) {
            short8 lf[3];
            #pragma unroll
            for (int i = 0; i < 3; ++i)
                lf[i] = *(const short8*)(lbase[i] + c * CHUNK_BYTES);
            #pragma unroll
            for (int ct = 0; ct < 3; ++ct) {
                short8 df = *(const short8*)&img[xi(ct * 16 + lm, c * 32 + lg * 8)];
                #pragma unroll
                for (int i = 0; i < 3; ++i)
                    acc[i][ct] = __builtin_amdgcn_mfma_f32_16x16x32_bf16(
                        lf[i], df, acc[i][ct], 0, 0, 0);
            }
        }
    };

    // lane holds 4 consecutive n (n0 = tile*16+lg*4) at col m=ct*16+lm
    auto store_acc = [&]() {
        #pragma unroll
        for (int i = 0; i < 3; ++i) {
            int n0 = (w * 3 + i) * 16 + lg * 4;
            #pragma unroll
            for (int ct = 0; ct < 3; ++ct) {
                ushort4 u;
                u.x = f2bf(acc[i][ct][0]); u.y = f2bf(acc[i][ct][1]);
                u.z = f2bf(acc[i][ct][2]); u.w = f2bf(acc[i][ct][3]);
                *(ushort4*)&img[xi(ct * 16 + lm, n0)] = u;
            }
        }
    };

    // n-minor global: dst[g][t*328+n], b128 LDS read + 16B coalesced store
    auto copy_out = [&](unsigned short* dst) {
        for (int i = tid; i < 4 * SEQ * 41; i += 448) {   // 1968
            int gl = i / 492, r2 = i - gl * 492;
            int t = r2 / 41, oct = r2 - t * 41;
            int m = gl * SEQ + t;
            short8 v = *(const short8*)&img[xi(m, oct * 8)];
            *(short8*)&dst[(size_t)(g0 + gl) * GROW + t * NROW + oct * 8] = v;
        }
    };

    // ---- GEMM1: Y = L * X ----
    zero_acc();
    gemm();
    __syncthreads();              // all img (X) reads complete
    store_acc();                  // Y -> img
    __syncthreads();              // Y image complete
    copy_out(Yg);                 // coalesced Y writeout

    // ---- GEMM2: Z = L * Y (stale X cols j>=336 killed by L zero cols) ----
    zero_acc();
    gemm();
    __syncthreads();              // all img (Y) reads complete
    store_acc();                  // Z -> img
    __syncthreads();              // Z image complete
    copy_out(Zg);                 // coalesced Z writeout
}

// ---- Phase B (r8-validated, unchanged): out = W(64x192) x [X;Y;Z] + bias ----
__global__ __launch_bounds__(256) void mix2(
        const float* __restrict__ x,
        const unsigned short* __restrict__ Yg,
        const unsigned short* __restrict__ Zg,
        const unsigned short* __restrict__ wflat,
        const float* __restrict__ bias,
        float* __restrict__ out) {
    __shared__ __align__(16) unsigned char Bl[96 * 400];   // 38400 B
    const int tid = threadIdx.x;
    int lin = blockIdx.x;
    lin = (lin & 7) * 328 + (lin >> 3);          // XCD swizzle (2624 = 8*328)
    const int b = lin / 41;
    const int tile = lin - b * 41;
    const int nt0 = tile * 96;
    const int nn0 = tile * 8;

    for (int i = tid; i < 576; i += 256) {
        int kk = i / 192;                        // 0=X, 1=Y, 2=Z
        int r2 = i - kk * 192;
        int cq = r2 / 12;
        int tc = r2 - cq * 12;
        int k0 = kk * 64 + cq * 4;
        unsigned short hv[4][8];
        if (kk == 0) {
            int nt = nt0 + tc * 8;
            #pragma unroll
            for (int r = 0; r < 4; ++r) {
                const float* sp = x + ((size_t)b * 64 + cq * 4 + r) * NT + nt;
                float4 v0 = (nt <= NT - 4) ? *(const float4*)sp : make_float4(0.f,0.f,0.f,0.f);
                float4 v1 = (nt <= NT - 8) ? *(const float4*)(sp + 4) : make_float4(0.f,0.f,0.f,0.f);
                hv[r][0] = f2bf(v0.x); hv[r][1] = f2bf(v0.y);
                hv[r][2] = f2bf(v0.z); hv[r][3] = f2bf(v0.w);
                hv[r][4] = f2bf(v1.x); hv[r][5] = f2bf(v1.y);
                hv[r][6] = f2bf(v1.z); hv[r][7] = f2bf(v1.w);
            }
        } else {
            const unsigned short* base = (kk == 1) ? Yg : Zg;
            #pragma unroll
            for (int r = 0; r < 4; ++r) {
                short8 s = *(const short8*)(base + ((size_t)b * 64 + cq * 4 + r) * GROW
                                            + tc * NROW + nn0);
                hv[r][0] = (unsigned short)s[0]; hv[r][1] = (unsigned short)s[1];
                hv[r][2] = (unsigned short)s[2]; hv[r][3] = (unsigned short)s[3];
                hv[r][4] = (unsigned short)s[4]; hv[r][5] = (unsigned short)s[5];
                hv[r][6] = (unsigned short)s[6]; hv[r][7] = (unsigned short)s[7];
            }
        }
        const int slot = k0 >> 3;
        const int half = (k0 & 4) << 1;          // byte offset within 16B slot
        #pragma unroll
        for (int jj = 0; jj < 8; ++jj) {
            int q = (kk == 0) ? (tc * 8 + jj) : (jj * 12 + tc);
            int sl = (slot & ~3) | ((slot & 3) ^ ((q >> 3) & 3));
            ushort4 o;
            o.x = hv[0][jj]; o.y = hv[1][jj]; o.z = hv[2][jj]; o.w = hv[3][jj];
            *(ushort4*)(Bl + q * 400 + sl * 16 + half) = o;
        }
    }
    __syncthreads();

    const int w = tid >> 6;
    const int l = tid & 63;
    const int lm = l & 15, lg = l >> 4;

    floatx4 acc[6];
    #pragma unroll
    for (int i = 0; i < 6; ++i) acc[i] = (floatx4){0.f, 0.f, 0.f, 0.f};

    const int arow = w * 16 + lm;
    const unsigned short* Ab = wflat + arow * 192;
    #pragma unroll
    for (int ks = 0; ks < 6; ++ks) {
        short8 a = *(const short8*)(Ab + ks * 32 + lg * 8);
        #pragma unroll
        for (int ni = 0; ni < 6; ++ni) {
            int q = ni * 16 + lm;
            short8 bb = *(const short8*)(Bl + q * 400 + (4 * ks + (lg ^ ((q >> 3) & 3))) * 16);
            acc[ni] = __builtin_amdgcn_mfma_f32_16x16x32_bf16(a, bb, acc[ni], 0, 0, 0);
        }
    }

    float br[4];
    #pragma unroll
    for (int j = 0; j < 4; ++j) br[j] = bias[w * 16 + lg * 4 + j];
    #pragma unroll
    for (int ni = 0; ni < 6; ++ni) {
        int nt = nt0 + ni * 16 + lm;
        if (nt < NT) {
            float* op = out + ((size_t)b * 64 + w * 16 + lg * 4) * NT + nt;
            #pragma unroll
            for (int j = 0; j < 4; ++j) op[(size_t)j * NT] = acc[ni][j] + br[j];
        }
    }
}

extern "C" void kernel_launch(void* const* d_in, const int* in_sizes, int n_in,
                              void* d_out, int out_size, void* d_ws, size_t ws_size,
                              hipStream_t stream) {
    const float* x   = (const float*)d_in[0];
    const float* adj = (const float*)d_in[1];
    const float* W   = (const float*)d_in[2];
    const float* b   = (const float*)d_in[3];
    float* out = (float*)d_out;

    char* ws = (char*)d_ws;
    // layout (bytes), 128B-aligned Y/Z:
    //   0        : dis    (1312)
    //   1312     : Lg2    (11*12288 bf16 = 270336) -> 271648
    //   271648   : wflat  (24576) -> 296224, pad to 296320
    //   296320   : Y'     (4096*3936 bf16 = 32243712) -> 32540032
    //   32540032 : Z'     (32243712) -> 64783744 (~61.8 MiB)
    float* dis           = (float*)(ws + 0);
    unsigned short* Lg2  = (unsigned short*)(ws + 1312);
    unsigned short* wflat= (unsigned short*)(ws + 271648);
    unsigned short* Yg   = (unsigned short*)(ws + 296320);
    unsigned short* Zg   = (unsigned short*)(ws + 32540032);

    calc_dis<<<NND, 64, 0, stream>>>(adj, dis);
    build_all<<<576, 256, 0, stream>>>(adj, dis, Lg2, W, wflat);
    cheb_fused<<<1024, 448, 0, stream>>>(x, Lg2, Yg, Zg);
    mix2<<<2624, 256, 0, stream>>>(x, Yg, Zg, wflat, b, out);
}